// Round 2
// baseline (452.739 us; speedup 1.0000x reference)
//
#include <hip/hip_runtime.h>
#include <hip/hip_bf16.h>
#include <cstdint>
#include <cstddef>

// Problem: B=16, N=128, D=S=128, hidden=256. fp32 I/O, bf16 MFMA internals.
// Pipeline:
//   proj_kernel : Pa/Qab/Pm/Qmb node projections (folds b1a/b1m, and the
//                 un-BN constant c into Qmb) -> ws (fp32)
//   wswz_kernel : fp32->bf16 transpose+XOR-swizzle of W1a[256:384], W2a,
//                 W1m[256:384] (rows scaled by 1/sc_e = un-BN fold), W2m -> ws
//   edge_mlp    : per (b,p) tile of 128 rows: relu(X@W1ae + Pa[q]+Qab[p]) @ W2a
//                 -> relu -> *mask -> edge BN -> FINAL fp32 edges in d_out
//   msg_mlp     : reads BN'd fp32 edges (un-BN folded into weights/bias),
//                 message MLP, relu*mask, column-reduce over q -> agg (fp32 ws)
//   update      : VALU update-MLP(concat(nodes,agg)) + node BN -> d_out nodes
// ws usage: 4x2MB proj + 1MB agg + 256KB weights = 9.25 MB.

typedef __attribute__((ext_vector_type(8))) __bf16 bf16x8;
typedef __attribute__((ext_vector_type(4))) float f32x4;

#define GLDS(gp, lp)                                                        \
  __builtin_amdgcn_global_load_lds(                                         \
      (const __attribute__((address_space(1))) void*)(gp),                  \
      (__attribute__((address_space(3))) void*)(lp), 16, 0, 0)

__device__ inline bf16x8 load8_cvt(const float* __restrict__ p) {
  const float4 a = *(const float4*)p;
  const float4 b = *(const float4*)(p + 4);
  bf16x8 r;
  r[0] = (__bf16)a.x; r[1] = (__bf16)a.y; r[2] = (__bf16)a.z; r[3] = (__bf16)a.w;
  r[4] = (__bf16)b.x; r[5] = (__bf16)b.y; r[6] = (__bf16)b.z; r[7] = (__bf16)b.w;
  return r;
}

// ---------------- prep: node projections (fp32) ----------------
// mat 0: Pa  = nodes @ W1a[0:128]        (state_i side, varies per row q)
// mat 1: Qab = nodes @ W1a[128:256]+b1a  (state_j side, block-constant p)
// mat 2: Pm  = nodes @ W1m[0:128]
// mat 3: Qmb = nodes @ W1m[128:256]+b1m + c, c = -(sh_e/sc_e)@W1m[256:384]
__global__ void __launch_bounds__(256) proj_kernel(
    const float* __restrict__ nodes, const float* __restrict__ W1a,
    const float* __restrict__ b1a, const float* __restrict__ W1m,
    const float* __restrict__ b1m, const float* __restrict__ ge,
    const float* __restrict__ be, const float* __restrict__ me,
    const float* __restrict__ ve, float* __restrict__ outP) {
  __shared__ float x[8][128];
  const int mat = blockIdx.y;
  const int t = threadIdx.x;
  const float* W = (mat < 2 ? W1a : W1m) + ((mat & 1) ? 128 * 256 : 0);
  float* out = outP + (size_t)mat * (2048 * 256);
  const int r0 = blockIdx.x * 8;
  for (int i = t; i < 1024; i += 256)
    x[i >> 7][i & 127] = nodes[r0 * 128 + i];
  __syncthreads();
  float bv = 0.f;
  if (mat == 1) bv = b1a[t];
  if (mat == 3) {
    bv = b1m[t];
    const float* We = W1m + 65536;  // rows 256..383 (edge part)
    float cc = 0.f;
    for (int k = 0; k < 128; ++k) {
      float sc = ge[k] * rsqrtf(ve[k] + 1e-3f);
      float sh = be[k] - me[k] * sc;
      cc -= (sh / sc) * We[k * 256 + t];
    }
    bv += cc;
  }
  float acc[8];
#pragma unroll
  for (int r = 0; r < 8; ++r) acc[r] = bv;
  for (int k = 0; k < 128; ++k) {
    float w = W[k * 256 + t];
#pragma unroll
    for (int r = 0; r < 8; ++r) acc[r] += x[r][k] * w;
  }
  for (int r = 0; r < 8; ++r) out[(size_t)(r0 + r) * 256 + t] = acc[r];
}

// ---------------- prep: weight fp32->bf16 transpose + swizzle ----------------
// W1-type (K=128, N=256): dst[n*128 + gs*8 + (k&7)], g=k>>3, gs=(g&8)|((g^n)&7).
// W2-type (K=256, N=128): dst[(k>>6)*8192 + n*64 + (((k>>3)^n)&7)*8 + (k&7)].
// mat2 (W1me) rows are scaled by 1/sc_e[k] (un-BN fold).
__global__ void __launch_bounds__(256) wswz_kernel(
    const float* __restrict__ W1a, const float* __restrict__ W2a,
    const float* __restrict__ W1m, const float* __restrict__ W2m,
    const float* __restrict__ ge, const float* __restrict__ ve,
    __hip_bfloat16* __restrict__ dstp) {
  __bf16* dst = (__bf16*)dstp;
  const int mat = blockIdx.y;
  const float* src;
  __bf16* d;
  int nsh;
  if (mat == 0)      { src = W1a + 65536; d = dst;         nsh = 8; }
  else if (mat == 1) { src = W2a;         d = dst + 32768; nsh = 7; }
  else if (mat == 2) { src = W1m + 65536; d = dst + 65536; nsh = 8; }
  else               { src = W2m;         d = dst + 98304; nsh = 7; }
  const int nmask = (1 << nsh) - 1;
  const int base = (blockIdx.x * 256 + threadIdx.x) * 4;
#pragma unroll
  for (int i = 0; i < 4; ++i) {
    int s = base + i;
    int k = s >> nsh, n = s & nmask;
    float v = src[s];
    if (mat == 2) v *= sqrtf(ve[k] + 1e-3f) / ge[k];  // 1/sc_e[k]
    int g = k >> 3;
    if (nsh == 8) {
      int gs = (g & 8) | ((g ^ n) & 7);
      d[n * 128 + gs * 8 + (k & 7)] = (__bf16)v;
    } else {
      int gs = (g ^ n) & 7;
      d[((k >> 6) << 13) + (n << 6) + (gs << 3) + (k & 7)] = (__bf16)v;
    }
  }
}

// ---------------- kernel A: edge MLP -> BN'd fp32 edges (final) ----------------
__global__ void __launch_bounds__(256, 2) edge_mlp_kernel(
    const float* __restrict__ edges, const float* __restrict__ mask,
    const float* __restrict__ b2a, const float* __restrict__ ge,
    const float* __restrict__ be, const float* __restrict__ me,
    const float* __restrict__ ve, const float* __restrict__ Pa,
    const float* __restrict__ Qab, const __hip_bfloat16* __restrict__ Wsw,
    float* __restrict__ edges_out) {
  __shared__ __align__(16) char sW1h[16384];
  __shared__ __align__(16) char sW2h[16384];
  __shared__ __align__(16) char sH1q[16384];
  __shared__ float sQ[256];
  __shared__ float sB2[128];
  __shared__ float sMask[128];
  __shared__ float sScE[128];
  __shared__ float sShE[128];

  const int t = threadIdx.x;
  const int lane = t & 63, wv = t >> 6;
  const int cl = lane & 15, qd = lane >> 4;
  const int m0 = wv * 32;

  if (t < 128) {
    sB2[t] = b2a[t];
    float sc = ge[t] * rsqrtf(ve[t] + 1e-3f);
    sScE[t] = sc;
    sShE[t] = be[t] - me[t] * sc;
  }

  const int bb = blockIdx.x >> 5;
  const int p0 = (blockIdx.x & 31) * 4;
  const char* gW1base = (const char*)Wsw;            // Wt1ae 32KB
  const char* gW2base = (const char*)(Wsw + 32768);  // Wt2a  32KB

  for (int tp = 0; tp < 4; ++tp) {
    const int p = p0 + tp;
    __syncthreads();  // protect sQ/sMask rewrite vs previous tile readers
    sQ[t] = Qab[((bb << 7) + p) * 256 + t];
    if (t < 128) sMask[t] = mask[(bb << 14) + (p << 7) + t];

    const float* Xb = edges + ((size_t)((bb << 14) + (p << 7)) << 7);
    bf16x8 xf[2][4];  // A-frags (edge features), cached for whole tile
#pragma unroll
    for (int mt = 0; mt < 2; ++mt)
#pragma unroll
      for (int ks = 0; ks < 4; ++ks)
        xf[mt][ks] = load8_cvt(Xb + (m0 + mt * 16 + cl) * 128 + ks * 32 + qd * 8);

    f32x4 ne[2][8];
#pragma unroll
    for (int mt = 0; mt < 2; ++mt)
#pragma unroll
      for (int nt = 0; nt < 8; ++nt) {
        float bv = sB2[nt * 16 + cl];
        ne[mt][nt] = (f32x4){bv, bv, bv, bv};
      }

    for (int h = 0; h < 4; ++h) {
      __syncthreads();  // previous slice users done
      {
        const char* gW1 = gW1base + h * 16384;
        const char* gW2 = gW2base + h * 16384;
        for (int o = wv * 1024; o < 16384; o += 4096) {
          GLDS(gW1 + o + lane * 16, sW1h + o);
          GLDS(gW2 + o + lane * 16, sW2h + o);
        }
      }
      // GEMM1 acc init from Pa[q]+Qab[p] (overlaps staging)
      f32x4 a1[2][4];
#pragma unroll
      for (int mt = 0; mt < 2; ++mt)
#pragma unroll
        for (int nt = 0; nt < 4; ++nt) {
          const int col = h * 64 + nt * 16 + cl;
          const int mrow = m0 + mt * 16 + qd * 4;
          const float qv = sQ[col];
          const float* pa = Pa + (size_t)((bb << 7) + mrow) * 256 + col;
          a1[mt][nt] = (f32x4){pa[0] + qv, pa[256] + qv, pa[512] + qv, pa[768] + qv};
        }
      __syncthreads();  // weights staged
#pragma unroll
      for (int ks = 0; ks < 4; ++ks)
#pragma unroll
        for (int nt = 0; nt < 4; ++nt) {
          const int nl = nt * 16 + cl;
          const int g = ks * 4 + qd;
          const int gs = (g & 8) | ((g ^ nl) & 7);
          bf16x8 bw = *(const bf16x8*)(sW1h + nl * 256 + gs * 16);
          a1[0][nt] = __builtin_amdgcn_mfma_f32_16x16x32_bf16(xf[0][ks], bw, a1[0][nt], 0, 0, 0);
          a1[1][nt] = __builtin_amdgcn_mfma_f32_16x16x32_bf16(xf[1][ks], bw, a1[1][nt], 0, 0, 0);
        }
      // relu -> bf16 -> swizzled H1 quarter
#pragma unroll
      for (int mt = 0; mt < 2; ++mt)
#pragma unroll
        for (int nt = 0; nt < 4; ++nt) {
          const int kq = nt * 16 + cl;
#pragma unroll
          for (int r = 0; r < 4; ++r) {
            const int m = m0 + mt * 16 + qd * 4 + r;
            float v = a1[mt][nt][r];
            v = v > 0.f ? v : 0.f;
            const int gs = ((kq >> 3) ^ m) & 7;
            *(__bf16*)(sH1q + m * 128 + gs * 16 + (kq & 7) * 2) = (__bf16)v;
          }
        }
      __syncthreads();  // H1 visible
      bf16x8 hf[2][2];
#pragma unroll
      for (int mt = 0; mt < 2; ++mt)
#pragma unroll
        for (int ks = 0; ks < 2; ++ks) {
          const int m = m0 + mt * 16 + cl;
          const int g = ks * 4 + qd;
          const int gs = (g ^ m) & 7;
          hf[mt][ks] = *(const bf16x8*)(sH1q + m * 128 + gs * 16);
        }
#pragma unroll
      for (int ks = 0; ks < 2; ++ks)
#pragma unroll
        for (int nt = 0; nt < 8; ++nt) {
          const int n = nt * 16 + cl;
          const int g = ks * 4 + qd;
          const int gs = (g ^ n) & 7;
          bf16x8 bw = *(const bf16x8*)(sW2h + n * 128 + gs * 16);
          ne[0][nt] = __builtin_amdgcn_mfma_f32_16x16x32_bf16(hf[0][ks], bw, ne[0][nt], 0, 0, 0);
          ne[1][nt] = __builtin_amdgcn_mfma_f32_16x16x32_bf16(hf[1][ks], bw, ne[1][nt], 0, 0, 0);
        }
    }
    // epilogue: relu * mask -> edge BN -> FINAL fp32 edges
    float* Ob = edges_out + ((size_t)((bb << 14) + (p << 7)) << 7);
#pragma unroll
    for (int mt = 0; mt < 2; ++mt)
#pragma unroll
      for (int nt = 0; nt < 8; ++nt) {
        const int col = nt * 16 + cl;
        const float sc = sScE[col], sh = sShE[col];
#pragma unroll
        for (int r = 0; r < 4; ++r) {
          const int m = m0 + mt * 16 + qd * 4 + r;
          float v = ne[mt][nt][r];
          v = v > 0.f ? v : 0.f;
          Ob[m * 128 + col] = (v * sMask[m]) * sc + sh;
        }
      }
  }
}

// ---------- kernel B: message MLP (un-BN folded) + aggregate ----------
__global__ void __launch_bounds__(256, 2) msg_mlp_kernel(
    const float* __restrict__ mask, const float* __restrict__ b2m,
    const float* __restrict__ Pm, const float* __restrict__ Qmb,
    const __hip_bfloat16* __restrict__ Wsw, const float* __restrict__ Yedges,
    float* __restrict__ agg) {
  __shared__ __align__(16) char sW1h[16384];
  __shared__ __align__(16) char sW2h[16384];
  __shared__ __align__(16) char sH1q[16384];
  __shared__ float sQ[256];
  __shared__ float sB2[128];
  __shared__ float sMask[128];
  __shared__ float sAgg[512];

  const int t = threadIdx.x;
  const int lane = t & 63, wv = t >> 6;
  const int cl = lane & 15, qd = lane >> 4;
  const int m0 = wv * 32;

  if (t < 128) sB2[t] = b2m[t];

  const int bb = blockIdx.x >> 5;
  const int p0 = (blockIdx.x & 31) * 4;
  const char* gW1base = (const char*)Wsw;            // Wt1me (scaled)
  const char* gW2base = (const char*)(Wsw + 32768);  // Wt2m

  for (int tp = 0; tp < 4; ++tp) {
    const int p = p0 + tp;
    __syncthreads();
    sQ[t] = Qmb[((bb << 7) + p) * 256 + t];
    if (t < 128) sMask[t] = mask[(bb << 14) + (p << 7) + t];

    const float* Xb = Yedges + ((size_t)((bb << 14) + (p << 7)) << 7);
    bf16x8 xf[2][4];
#pragma unroll
    for (int mt = 0; mt < 2; ++mt)
#pragma unroll
      for (int ks = 0; ks < 4; ++ks)
        xf[mt][ks] = load8_cvt(Xb + (m0 + mt * 16 + cl) * 128 + ks * 32 + qd * 8);

    f32x4 ms[2][8];
#pragma unroll
    for (int mt = 0; mt < 2; ++mt)
#pragma unroll
      for (int nt = 0; nt < 8; ++nt) {
        float bv = sB2[nt * 16 + cl];
        ms[mt][nt] = (f32x4){bv, bv, bv, bv};
      }

    for (int h = 0; h < 4; ++h) {
      __syncthreads();
      {
        const char* gW1 = gW1base + h * 16384;
        const char* gW2 = gW2base + h * 16384;
        for (int o = wv * 1024; o < 16384; o += 4096) {
          GLDS(gW1 + o + lane * 16, sW1h + o);
          GLDS(gW2 + o + lane * 16, sW2h + o);
        }
      }
      f32x4 a1[2][4];
#pragma unroll
      for (int mt = 0; mt < 2; ++mt)
#pragma unroll
        for (int nt = 0; nt < 4; ++nt) {
          const int col = h * 64 + nt * 16 + cl;
          const int mrow = m0 + mt * 16 + qd * 4;
          const float qv = sQ[col];
          const float* pa = Pm + (size_t)((bb << 7) + mrow) * 256 + col;
          a1[mt][nt] = (f32x4){pa[0] + qv, pa[256] + qv, pa[512] + qv, pa[768] + qv};
        }
      __syncthreads();
#pragma unroll
      for (int ks = 0; ks < 4; ++ks)
#pragma unroll
        for (int nt = 0; nt < 4; ++nt) {
          const int nl = nt * 16 + cl;
          const int g = ks * 4 + qd;
          const int gs = (g & 8) | ((g ^ nl) & 7);
          bf16x8 bw = *(const bf16x8*)(sW1h + nl * 256 + gs * 16);
          a1[0][nt] = __builtin_amdgcn_mfma_f32_16x16x32_bf16(xf[0][ks], bw, a1[0][nt], 0, 0, 0);
          a1[1][nt] = __builtin_amdgcn_mfma_f32_16x16x32_bf16(xf[1][ks], bw, a1[1][nt], 0, 0, 0);
        }
#pragma unroll
      for (int mt = 0; mt < 2; ++mt)
#pragma unroll
        for (int nt = 0; nt < 4; ++nt) {
          const int kq = nt * 16 + cl;
#pragma unroll
          for (int r = 0; r < 4; ++r) {
            const int m = m0 + mt * 16 + qd * 4 + r;
            float v = a1[mt][nt][r];
            v = v > 0.f ? v : 0.f;
            const int gs = ((kq >> 3) ^ m) & 7;
            *(__bf16*)(sH1q + m * 128 + gs * 16 + (kq & 7) * 2) = (__bf16)v;
          }
        }
      __syncthreads();
      bf16x8 hf[2][2];
#pragma unroll
      for (int mt = 0; mt < 2; ++mt)
#pragma unroll
        for (int ks = 0; ks < 2; ++ks) {
          const int m = m0 + mt * 16 + cl;
          const int g = ks * 4 + qd;
          const int gs = (g ^ m) & 7;
          hf[mt][ks] = *(const bf16x8*)(sH1q + m * 128 + gs * 16);
        }
#pragma unroll
      for (int ks = 0; ks < 2; ++ks)
#pragma unroll
        for (int nt = 0; nt < 8; ++nt) {
          const int n = nt * 16 + cl;
          const int g = ks * 4 + qd;
          const int gs = (g ^ n) & 7;
          bf16x8 bw = *(const bf16x8*)(sW2h + n * 128 + gs * 16);
          ms[0][nt] = __builtin_amdgcn_mfma_f32_16x16x32_bf16(hf[0][ks], bw, ms[0][nt], 0, 0, 0);
          ms[1][nt] = __builtin_amdgcn_mfma_f32_16x16x32_bf16(hf[1][ks], bw, ms[1][nt], 0, 0, 0);
        }
    }
    // epilogue: relu * mask, column-sum over the tile's 128 rows (all q)
#pragma unroll
    for (int nt = 0; nt < 8; ++nt) {
      float s = 0.f;
#pragma unroll
      for (int mt = 0; mt < 2; ++mt)
#pragma unroll
        for (int r = 0; r < 4; ++r) {
          const int m = m0 + mt * 16 + qd * 4 + r;
          float v = ms[mt][nt][r];
          v = v > 0.f ? v : 0.f;
          s += v * sMask[m];
        }
      s += __shfl_xor(s, 16);
      s += __shfl_xor(s, 32);
      if (lane < 16) sAgg[wv * 128 + nt * 16 + lane] = s;
    }
    __syncthreads();
    if (t < 128)
      agg[((bb << 7) + p) * 128 + t] =
          sAgg[t] + sAgg[128 + t] + sAgg[256 + t] + sAgg[384 + t];
  }
}

// ---------------- kernel C: update MLP + node BN (VALU, tiny) ----------------
__global__ void __launch_bounds__(256) update_kernel(
    const float* __restrict__ nodes, const float* __restrict__ agg,
    const float* __restrict__ W1u, const float* __restrict__ b1u,
    const float* __restrict__ W2u, const float* __restrict__ b2u,
    const float* __restrict__ gn, const float* __restrict__ btn,
    const float* __restrict__ mn, const float* __restrict__ vn,
    float* __restrict__ out) {
  __shared__ float x[8][256];
  __shared__ float hh[8][256];
  const int t = threadIdx.x;
  const int r0 = blockIdx.x * 8;
  for (int i = t; i < 2048; i += 256) {
    int r = i >> 8, c = i & 255;
    x[r][c] = (c < 128) ? nodes[(r0 + r) * 128 + c] : agg[(r0 + r) * 128 + (c - 128)];
  }
  __syncthreads();
  float acc[8];
  {
    float bv = b1u[t];
#pragma unroll
    for (int r = 0; r < 8; ++r) acc[r] = bv;
  }
  for (int k = 0; k < 256; ++k) {
    float w = W1u[k * 256 + t];
#pragma unroll
    for (int r = 0; r < 8; ++r) acc[r] += x[r][k] * w;
  }
#pragma unroll
  for (int r = 0; r < 8; ++r) hh[r][t] = acc[r] > 0.f ? acc[r] : 0.f;
  __syncthreads();
  const int j = t & 127, half = t >> 7;
  float a2[4];
  {
    float bv = b2u[j];
#pragma unroll
    for (int r = 0; r < 4; ++r) a2[r] = bv;
  }
  for (int k = 0; k < 256; ++k) {
    float w = W2u[k * 128 + j];
#pragma unroll
    for (int r = 0; r < 4; ++r) a2[r] += hh[half * 4 + r][k] * w;
  }
  float sc = gn[j] * rsqrtf(vn[j] + 1e-3f);
  float sh = btn[j] - mn[j] * sc;
#pragma unroll
  for (int r = 0; r < 4; ++r) {
    float v = a2[r] > 0.f ? a2[r] : 0.f;
    out[(r0 + half * 4 + r) * 128 + j] = v * sc + sh;
  }
}

extern "C" void kernel_launch(void* const* d_in, const int* in_sizes, int n_in,
                              void* d_out, int out_size, void* d_ws,
                              size_t ws_size, hipStream_t stream) {
  (void)in_sizes; (void)n_in; (void)out_size; (void)ws_size;
  const float* nodes = (const float*)d_in[0];
  const float* edges = (const float*)d_in[1];
  const float* mask = (const float*)d_in[2];
  const float* W1a = (const float*)d_in[3];
  const float* b1a = (const float*)d_in[4];
  const float* W2a = (const float*)d_in[5];
  const float* b2a = (const float*)d_in[6];
  const float* W1m = (const float*)d_in[7];
  const float* b1m = (const float*)d_in[8];
  const float* W2m = (const float*)d_in[9];
  const float* b2m = (const float*)d_in[10];
  const float* W1u = (const float*)d_in[11];
  const float* b1u = (const float*)d_in[12];
  const float* W2u = (const float*)d_in[13];
  const float* b2u = (const float*)d_in[14];
  const float* gn = (const float*)d_in[15];
  const float* btn = (const float*)d_in[16];
  const float* mn = (const float*)d_in[17];
  const float* vn = (const float*)d_in[18];
  const float* ge = (const float*)d_in[19];
  const float* be = (const float*)d_in[20];
  const float* me = (const float*)d_in[21];
  const float* ve = (const float*)d_in[22];

  float* out_nodes = (float*)d_out;
  float* out_edges = (float*)d_out + 262144;

  char* ws = (char*)d_ws;
  float* Pa = (float*)(ws);
  float* Qab = (float*)(ws + ((size_t)1 << 21));
  float* Pm = (float*)(ws + ((size_t)2 << 21));
  float* Qmb = (float*)(ws + ((size_t)3 << 21));
  float* agg = (float*)(ws + ((size_t)4 << 21));
  __hip_bfloat16* Wsw = (__hip_bfloat16*)(ws + ((size_t)4 << 21) + ((size_t)1 << 20));

  proj_kernel<<<dim3(256, 4), 256, 0, stream>>>(nodes, W1a, b1a, W1m, b1m, ge,
                                                be, me, ve, Pa);
  wswz_kernel<<<dim3(32, 4), 256, 0, stream>>>(W1a, W2a, W1m, W2m, ge, ve, Wsw);
  edge_mlp_kernel<<<512, 256, 0, stream>>>(edges, mask, b2a, ge, be, me, ve, Pa,
                                           Qab, Wsw, out_edges);
  msg_mlp_kernel<<<512, 256, 0, stream>>>(mask, b2m, Pm, Qmb, Wsw + 65536,
                                          out_edges, agg);
  update_kernel<<<256, 256, 0, stream>>>(nodes, agg, W1u, b1u, W2u, b2u, gn, btn,
                                         mn, vn, out_nodes);
}